// Round 13
// baseline (149.044 us; speedup 1.0000x reference)
//
#include <hip/hip_runtime.h>
#include <stdint.h>

#define TT 2048
#define DD 768
#define NHEAD 12
#define DH 64
#define MM 8192   // B*T
#define DP 80     // padded head dim (64 data + 6 bias + 10 zero)

typedef __attribute__((ext_vector_type(8))) short bf16x8;
typedef __attribute__((ext_vector_type(4))) float f32x4;
typedef __attribute__((ext_vector_type(16))) float f32x16;
typedef __attribute__((ext_vector_type(2))) unsigned int u32x2v;
typedef unsigned short u16;

#define GAS __attribute__((address_space(1)))
#define LAS __attribute__((address_space(3)))

static __device__ __forceinline__ void gload16(const void* g, void* l) {
  __builtin_amdgcn_global_load_lds((const GAS uint32_t*)g, (LAS uint32_t*)l, 16, 0, 0);
}

static __device__ __forceinline__ u16 f2b(float f) {
  union { float f; uint32_t u; } x; x.f = f;
  uint32_t r = x.u + 0x7fffu + ((x.u >> 16) & 1u);
  return (u16)(r >> 16);
}
static __device__ __forceinline__ float b2f(u16 v) {
  union { uint32_t u; float f; } x; x.u = ((uint32_t)v) << 16; return x.f;
}

#if __has_builtin(__builtin_amdgcn_exp2f)
#define EXP2(x) __builtin_amdgcn_exp2f(x)
#else
#define EXP2(x) exp2f(x)
#endif

static __device__ __forceinline__ void pswap(uint32_t& a, uint32_t& b) {
#if __has_builtin(__builtin_amdgcn_permlane32_swap)
  u32x2v r = __builtin_amdgcn_permlane32_swap(a, b, false, false);
  a = r[0]; b = r[1];
#else
  uint32_t ax = (uint32_t)__shfl_xor((int)a, 32, 64);
  uint32_t bx = (uint32_t)__shfl_xor((int)b, 32, 64);
  bool lo = (threadIdx.x & 32) == 0;
  uint32_t na = lo ? a : bx, nb = lo ? ax : b;
  a = na; b = nb;
#endif
}
static __device__ __forceinline__ float pswap_add(float x) {
  uint32_t a = __float_as_uint(x), b = a; pswap(a, b);
  return __uint_as_float(a) + __uint_as_float(b);
}
static __device__ __forceinline__ uint32_t cvtpk(float lo, float hi_) {
  uint32_t r;
  asm("v_cvt_pk_bf16_f32 %0, %1, %2" : "=v"(r) : "v"(lo), "v"(hi_));
  return r;
}
static __device__ __forceinline__ f32x16 mfma32(bf16x8 a, bf16x8 b, f32x16 c) {
  return __builtin_amdgcn_mfma_f32_32x32x16_bf16(a, b, c, 0, 0, 0);
}

// ---------------- convert f32 -> bf16 (pure streaming, 8 el/thread) ----------------
__global__ __launch_bounds__(256) void convert_kernel(
    const float* __restrict__ H, const float* __restrict__ wq,
    const float* __restrict__ wk, const float* __restrict__ wv,
    const float* __restrict__ wo,
    u16* __restrict__ Hb, u16* __restrict__ Wqkv, u16* __restrict__ Wob) {
  const size_t NHEL = (size_t)MM * DD;     // 6291456 (mult of 8)
  const size_t NW = (size_t)DD * DD;       // 589824  (mult of 8)
  size_t i = ((size_t)blockIdx.x * 256 + threadIdx.x) * 8;
  const float* src; u16* dst; size_t so, dofs;
  if (i < NHEL) { src = H; so = i; dst = Hb; dofs = i; }
  else if (i < NHEL + 3 * NW) {
    size_t j = i - NHEL; dst = Wqkv; dofs = j;
    if (j < NW) { src = wq; so = j; }
    else if (j < 2 * NW) { src = wk; so = j - NW; }
    else { src = wv; so = j - 2 * NW; }
  } else if (i < NHEL + 4 * NW) {
    size_t j = i - NHEL - 3 * NW; src = wo; so = j; dst = Wob; dofs = j;
  } else return;
  float4 v0 = *(const float4*)&src[so];
  float4 v1 = *(const float4*)&src[so + 4];
  union { u16 u[8]; uint4 v; } o;
  o.u[0] = f2b(v0.x); o.u[1] = f2b(v0.y); o.u[2] = f2b(v0.z); o.u[3] = f2b(v0.w);
  o.u[4] = f2b(v1.x); o.u[5] = f2b(v1.y); o.u[6] = f2b(v1.z); o.u[7] = f2b(v1.w);
  *(uint4*)&dst[dofs] = o.v;
}

// ---------------- GEMM (MODE 0): QKV proj, 128x128 tile, XCD-swizzled grid ----------------
__global__ __launch_bounds__(256) void gemm0_kernel(
    const u16* __restrict__ A, const u16* __restrict__ Bw,
    u16* __restrict__ Qp, u16* __restrict__ Kp, u16* __restrict__ Vt,
    const float* __restrict__ Pp, const float* __restrict__ Sp,
    const float* __restrict__ compat, const float* __restrict__ gamma) {
  __shared__ u16 SMEM[17408];                 // As(8192) + Bs(8192); Ct overlays (128*136)
  u16* As = SMEM;
  u16* Bs = SMEM + 8192;
  const int tid = threadIdx.x;
  const int lane = tid & 63, w = tid >> 6;
  const int wr = w >> 1, wc = w & 1;
  const int g = lane >> 4, r = lane & 15;
  const int lin = blockIdx.x;
  const int swz = (lin & 7) * 144 + (lin >> 3);
  const int m0 = (swz / 18) * 128, n0 = (swz % 18) * 128;

  f32x4 acc[4][4];
#pragma unroll
  for (int m = 0; m < 4; ++m)
#pragma unroll
    for (int n = 0; n < 4; ++n) acc[m][n] = (f32x4){0.f, 0.f, 0.f, 0.f};

  for (int ks = 0; ks < 12; ++ks) {
    const int k0 = ks * 64;
    __syncthreads();
#pragma unroll
    for (int ii = 0; ii < 4; ++ii) {
      int seg = (w * 4 + ii) * 64 + lane;
      int row = seg >> 3, cs = seg & 7;
      int csw = cs ^ (row & 7);
      // each gload16 covers 64 lanes x 16B = 1024B = 512 u16 -> dest stride *512
      gload16(&A[(size_t)(m0 + row) * DD + k0 + csw * 8], &As[(w * 4 + ii) * 512]);
      gload16(&Bw[(size_t)(n0 + row) * DD + k0 + csw * 8], &Bs[(w * 4 + ii) * 512]);
    }
    __syncthreads();
#pragma unroll
    for (int kk = 0; kk < 2; ++kk) {
      bf16x8 af[4], bfr[4];
#pragma unroll
      for (int m = 0; m < 4; ++m) {
        int row = wr * 64 + m * 16 + r;
        int ch = (kk * 4 + g) ^ (row & 7);
        af[m] = *(const bf16x8*)&As[row * 64 + ch * 8];
      }
#pragma unroll
      for (int n = 0; n < 4; ++n) {
        int row = wc * 64 + n * 16 + r;
        int ch = (kk * 4 + g) ^ (row & 7);
        bfr[n] = *(const bf16x8*)&Bs[row * 64 + ch * 8];
      }
#pragma unroll
      for (int m = 0; m < 4; ++m)
#pragma unroll
        for (int n = 0; n < 4; ++n)
          acc[m][n] = __builtin_amdgcn_mfma_f32_16x16x32_bf16(af[m], bfr[n], acc[m][n], 0, 0, 0);
    }
  }

  const int sel = n0 / DD;            // 0=Q 1=K 2=V  (tiles never straddle)
  const int e0b = n0 - sel * DD;      // head-block base, h0 = e0b>>6
  const int bb = m0 >> 11;            // batch
  const int tb = m0 & (TT - 1);       // token base (multiple of 128)
  __syncthreads();                    // all LDS reads of As/Bs done
#pragma unroll
  for (int m = 0; m < 4; ++m) {
#pragma unroll
    for (int n = 0; n < 4; ++n) {
#pragma unroll
      for (int reg = 0; reg < 4; ++reg) {
        float v = acc[m][n][reg];
        int t = wr * 64 + m * 16 + g * 4 + reg;   // local token 0..127
        int c = wc * 64 + n * 16 + r;             // local N col 0..127
        u16 bv = f2b(sel == 0 ? v * 0.18033688f : v);  // Q: *0.125*log2(e)
        if (sel < 2) SMEM[t * 136 + c] = bv;      // Ct[t][c]
        else         SMEM[c * 136 + t] = bv;      // Ct[dh][t] (transposed)
      }
    }
  }
  __syncthreads();
  if (sel < 2) {
    u16* base = (sel == 0) ? Qp : Kp;
    const int grp = tid >> 3, li = tid & 7;       // 32 groups x 8 lanes
#pragma unroll
    for (int it = 0; it < 8; ++it) {
      int chunk = it * 32 + grp;                  // 0..255
      int t = chunk & 127, hh = chunk >> 7;
      int h = (e0b >> 6) + hh;
      size_t row = ((size_t)(bb * NHEAD + h) * TT + tb + t) * DP;
      uint4 d = *(const uint4*)&SMEM[t * 136 + hh * 64 + li * 8];
      *(uint4*)&base[row + li * 8] = d;
    }
    // ---- bias dims 64..79: one (t,hh) chunk per thread, 32B each ----
    {
      const float L2E = 1.44269504f;
      int t = tid & 127, hh = tid >> 7;
      int h = (e0b >> 6) + hh;
      size_t ip = (size_t)bb * TT + tb + t;
      float p0 = Pp[ip * 2], p1 = Pp[ip * 2 + 1];
      union { u16 u[8]; uint4 v; } bias;
      union { u16 u[8]; uint4 v; } zz;
#pragma unroll
      for (int z = 0; z < 8; ++z) zz.u[z] = 0;
      if (sel == 0) {
        float c00 = compat[h * 4 + 0], c01 = compat[h * 4 + 1];
        float c10 = compat[h * 4 + 2], c11 = compat[h * 4 + 3];
        u16 q0 = f2b((p0 * c00 + p1 * c10) * L2E);
        u16 q1 = f2b((p0 * c01 + p1 * c11) * L2E);
        u16 gmb = f2b(gamma[0] * L2E);
        bias.u[0] = q0; bias.u[1] = q0; bias.u[2] = q1; bias.u[3] = q1;
        bias.u[4] = gmb; bias.u[5] = gmb; bias.u[6] = 0; bias.u[7] = 0;
      } else {
        float sv = Sp[ip];
        u16 p0h = f2b(p0); u16 p0l = f2b(p0 - b2f(p0h));
        u16 p1h = f2b(p1); u16 p1l = f2b(p1 - b2f(p1h));
        u16 svh = f2b(sv); u16 svl = f2b(sv - b2f(svh));
        bias.u[0] = p0h; bias.u[1] = p0l; bias.u[2] = p1h; bias.u[3] = p1l;
        bias.u[4] = svh; bias.u[5] = svl; bias.u[6] = 0; bias.u[7] = 0;
      }
      size_t row = ((size_t)(bb * NHEAD + h) * TT + tb + t) * DP;
      *(uint4*)&base[row + 64] = bias.v;
      *(uint4*)&base[row + 72] = zz.v;
    }
  } else {
    const int grp = tid >> 4, li = tid & 15;      // 16 groups x 16 lanes
#pragma unroll
    for (int it = 0; it < 8; ++it) {
      int c = it * 16 + grp;                      // 0..127
      int h = (e0b >> 6) + (c >> 6), dh = c & 63;
      size_t row = ((size_t)(bb * NHEAD + h)) * DH * TT + (size_t)dh * TT + tb;
      uint4 d = *(const uint4*)&SMEM[c * 136 + li * 8];
      *(uint4*)&Vt[row + li * 8] = d;
    }
  }
}

// ---------------- GEMM (MODE 1): out-proj, 64x128 tile, 768 blocks (3/CU) ----
__global__ __launch_bounds__(256) void gemm1_kernel(
    const u16* __restrict__ A, const u16* __restrict__ Bw,
    const float* __restrict__ bo, float* __restrict__ Out) {
  __shared__ u16 SMEM[12288];                 // As 64x64 (4096) + Bs 128x64 (8192)
  u16* As = SMEM;
  u16* Bs = SMEM + 4096;
  const int tid = threadIdx.x;
  const int lane = tid & 63, w = tid >> 6;
  const int wr = w & 1, wc = w >> 1;          // wave: 32(M) x 64(N)
  const int g = lane >> 4, r = lane & 15;
  const int m0 = blockIdx.x * 64, n0 = blockIdx.y * 128;

  f32x4 acc[2][4];
#pragma unroll
  for (int m = 0; m < 2; ++m)
#pragma unroll
    for (int n = 0; n < 4; ++n) acc[m][n] = (f32x4){0.f, 0.f, 0.f, 0.f};

  for (int ks = 0; ks < 12; ++ks) {
    const int k0 = ks * 64;
    __syncthreads();
#pragma unroll
    for (int i = 0; i < 6; ++i) {             // 24 chunks over 4 waves
      int idx = w + 4 * i;
      if (idx < 8) {                          // A chunks 0..7 (64 rows)
        int n = idx * 64 + lane;
        int row = n >> 3, cs = n & 7;
        int csw = cs ^ (row & 7);
        gload16(&A[(size_t)(m0 + row) * DD + k0 + csw * 8], &As[idx * 512]);
      } else {                                // B chunks 0..15 (128 rows)
        int j = idx - 8;
        int n = j * 64 + lane;
        int row = n >> 3, cs = n & 7;
        int csw = cs ^ (row & 7);
        gload16(&Bw[(size_t)(n0 + row) * DD + k0 + csw * 8], &Bs[j * 512]);
      }
    }
    __syncthreads();
#pragma unroll
    for (int kk = 0; kk < 2; ++kk) {
      bf16x8 af[2], bfr[4];
#pragma unroll
      for (int m = 0; m < 2; ++m) {
        int row = wr * 32 + m * 16 + r;
        int ch = (kk * 4 + g) ^ (row & 7);
        af[m] = *(const bf16x8*)&As[row * 64 + ch * 8];
      }
#pragma unroll
      for (int n = 0; n < 4; ++n) {
        int row = wc * 64 + n * 16 + r;
        int ch = (kk * 4 + g) ^ (row & 7);
        bfr[n] = *(const bf16x8*)&Bs[row * 64 + ch * 8];
      }
#pragma unroll
      for (int m = 0; m < 2; ++m)
#pragma unroll
        for (int n = 0; n < 4; ++n)
          acc[m][n] = __builtin_amdgcn_mfma_f32_16x16x32_bf16(af[m], bfr[n], acc[m][n], 0, 0, 0);
    }
  }

#pragma unroll
  for (int m = 0; m < 2; ++m) {
#pragma unroll
    for (int n = 0; n < 4; ++n) {
#pragma unroll
      for (int reg = 0; reg < 4; ++reg) {
        int gt = m0 + wr * 32 + m * 16 + g * 4 + reg;
        int e = n0 + wc * 64 + n * 16 + r;
        Out[(size_t)gt * DD + e] = acc[m][n][reg] + bo[e];
      }
    }
  }
}

// ---------------- attention: swapped QK^T, fixed-base softmax (m=0) ----------------
// R4-proven loop structure. VALU-trimmed: (1) per-tile s-init replaced by a
// loop-invariant ZERO C-operand on the first MFMA of each chain; (2) s0/s1
// QK chains interleaved (two independent dep-chains); (3) l partial-sum moved
// after PV so the adds run under the MFMA shadow.
#define QB 128
__global__ __launch_bounds__(256, 3) void attn_kernel(
    const u16* __restrict__ Qp, const u16* __restrict__ Kp, const u16* __restrict__ Vtb,
    u16* __restrict__ Ctx) {
  __shared__ u16 Ks[2][64 * 88];   // 64 rows x 176B (160B data + 16B pad-dup)
  __shared__ u16 Vs[2][64 * 64];   // [dh][key], source pre-swizzled
  const int tid = threadIdx.x, lane = tid & 63, w = tid >> 6;
  const int hi = lane >> 5, ql = lane & 31;
  const int bid = blockIdx.x;
  const int bh = bid % 48, qb = bid / 48;   // bh-major: same bh -> same XCD
  const int b = bh / NHEAD, h = bh % NHEAD;

  const char* KgB = (const char*)(Kp + (size_t)bh * TT * DP);
  const char* VgB = (const char*)(Vtb + (size_t)bh * DH * TT);
  const u16* Qg = Qp + (size_t)bh * TT * DP;

  const int q = qb * QB + w * 32 + ql;
  bf16x8 Qf[5];
#pragma unroll
  for (int kbl = 0; kbl < 5; ++kbl)
    Qf[kbl] = *(const bf16x8*)&Qg[(size_t)q * DP + (2 * kbl + hi) * 8];

  auto kofs = [&](int i) {
    int n = i * 64 + lane;
    int rr = (n * 2979) >> 15;       // n/11 exact for n<768
    int c = n - 11 * rr; if (c > 9) c = 9;
    return rr * 160 + c * 16;
  };
  auto vofs = [&](int j) {
    int n = j * 64 + lane;
    int dh = n >> 3, cs = n & 7;
    return dh * 4096 + (cs ^ (dh & 7)) * 16;
  };
  const int koff0 = kofs(w), koff1 = kofs(w + 4), koff2 = (w < 3) ? kofs(w + 8) : 0;
  const int voff0 = vofs(w), voff1 = vofs(w + 4);

  auto STAGE = [&](int nb, int t0) {
    const char* ksrc = KgB + (size_t)t0 * 160;
    char* kd = (char*)&Ks[nb][0];
    gload16(ksrc + koff0, kd + w * 1024);
    gload16(ksrc + koff1, kd + (w + 4) * 1024);
    if (w < 3) gload16(ksrc + koff2, kd + (w + 8) * 1024);
    const char* vsrc = VgB + (size_t)t0 * 2;
    char* vd = (char*)&Vs[nb][0];
    gload16(vsrc + voff0, vd + w * 1024);
    gload16(vsrc + voff1, vd + (w + 4) * 1024);
  };

  f32x16 o0, o1;
#pragma unroll
  for (int z = 0; z < 16; ++z) { o0[z] = 0.f; o1[z] = 0.f; }
  float l_st = 0.f;

  // loop-invariant zero C-operand (16 regs held zero; no per-tile movs)
  f32x16 ZERO;
#pragma unroll
  for (int z = 0; z < 16; ++z) ZERO[z] = 0.f;
  asm volatile("" : "+v"(ZERO));   // keep materialized

  STAGE(0, 0);

  for (int kt = 0; kt < 32; ++kt) {
    __syncthreads();                       // drains vmcnt: current buffers valid
    if (kt + 1 < 32) STAGE((kt + 1) & 1, (kt + 1) * 64);
    const u16* Kb_ = &Ks[kt & 1][0];
    const u16* Vb_ = &Vs[kt & 1][0];

    // S^T = K' * Q'^T : two interleaved independent chains (s0, s1)
    f32x16 s0, s1;
    __builtin_amdgcn_s_setprio(1);
    {
      bf16x8 a0 = *(const bf16x8*)&Kb_[ql * 88 + hi * 8];
      bf16x8 a1 = *(const bf16x8*)&Kb_[(ql + 32) * 88 + hi * 8];
      s0 = mfma32(a0, Qf[0], ZERO);
      s1 = mfma32(a1, Qf[0], ZERO);
    }
#pragma unroll
    for (int kbl = 1; kbl < 5; ++kbl) {
      bf16x8 a0 = *(const bf16x8*)&Kb_[ql * 88 + hi * 8 + kbl * 16];
      bf16x8 a1 = *(const bf16x8*)&Kb_[(ql + 32) * 88 + hi * 8 + kbl * 16];
      s0 = mfma32(a0, Qf[kbl], s0);
      s1 = mfma32(a1, Qf[kbl], s1);
    }
    __builtin_amdgcn_s_setprio(0);

    // P = exp2(S) directly (fixed base m=0)
    float p_[32];
#pragma unroll
    for (int z = 0; z < 16; ++z) p_[z] = EXP2(s0[z]);
#pragma unroll
    for (int z = 0; z < 16; ++z) p_[16 + z] = EXP2(s1[z]);

    // build PA fragments in-register (cvt_pk + permlane32_swap); PV
    __builtin_amdgcn_s_setprio(1);
#pragma unroll
    for (int ks = 0; ks < 4; ++ks) {
      const int base = ks * 8;
      uint32_t wa = cvtpk(p_[base + 0], p_[base + 1]);
      uint32_t wb = cvtpk(p_[base + 4], p_[base + 5]);
      uint32_t wc = cvtpk(p_[base + 2], p_[base + 3]);
      uint32_t wd = cvtpk(p_[base + 6], p_[base + 7]);
      pswap(wa, wb);
      pswap(wc, wd);
      union { uint32_t u[4]; bf16x8 v; } pa;
      pa.u[0] = wa; pa.u[1] = wc; pa.u[2] = wb; pa.u[3] = wd;
#pragma unroll
      for (int nb = 0; nb < 2; ++nb) {
        int row = ql + 32 * nb;
        bf16x8 vf = *(const bf16x8*)&Vb_[row * 64 + (((2 * ks + hi) ^ (ql & 7)) * 8)];
        if (nb == 0) o0 = mfma32(pa.v, vf, o0);
        else         o1 = mfma32(pa.v, vf, o1);
      }
    }
    __builtin_amdgcn_s_setprio(0);

    // l partial-sum after PV: VALU adds run under the MFMA shadow
    float ts = 0.f;
#pragma unroll
    for (int z = 0; z < 32; ++z) ts += p_[z];
    l_st += ts;
  }

  // epilogue: combine hi-halves of l once, broadcast 1/l from lane q2
  float lfull = pswap_add(l_st);            // lanes ql and ql+32 both hold l(q=ql)
  float invl = 1.0f / lfull;
#pragma unroll
  for (int z = 0; z < 16; ++z) {
    int q2 = (z & 3) + 8 * (z >> 2) + 4 * hi;
    float il = __uint_as_float(__builtin_amdgcn_ds_bpermute(q2 * 4, __float_as_uint(invl)));
    int qrow = qb * QB + w * 32 + q2;
    size_t rowb = ((size_t)b * TT + qrow) * DD + h * DH;
    Ctx[rowb + ql]      = f2b(o0[z] * il);
    Ctx[rowb + ql + 32] = f2b(o1[z] * il);
  }
}

extern "C" void kernel_launch(void* const* d_in, const int* in_sizes, int n_in,
                              void* d_out, int out_size, void* d_ws, size_t ws_size,
                              hipStream_t stream) {
  const float* H = (const float*)d_in[0];
  const float* p = (const float*)d_in[1];
  const float* s = (const float*)d_in[2];
  const float* wq = (const float*)d_in[3];
  const float* wk = (const float*)d_in[4];
  const float* wv = (const float*)d_in[5];
  const float* wo = (const float*)d_in[6];
  const float* bo = (const float*)d_in[7];
  const float* compat = (const float*)d_in[8];
  const float* gamma = (const float*)d_in[9];
  float* out = (float*)d_out;

  char* ws = (char*)d_ws;
  u16* Hb   = (u16*)(ws);               // 12,582,912 B (dead after gemm0 -> Ctx)
  u16* Wqkv = (u16*)(ws + 12582912);    //  3,538,944 B
  u16* Wob  = (u16*)(ws + 16121856);    //  1,179,648 B
  u16* Qpb  = (u16*)(ws + 17301504);    // 15,728,640 B  (B*H*T*80 bf16)
  u16* Kpb  = (u16*)(ws + 33030144);    // 15,728,640 B
  u16* Vtb  = (u16*)(ws + 48758784);    // 12,582,912 B  (written transposed by gemm0)
  u16* Ctx  = Hb;                       // alias: Hb dead after gemm0
  // total 61,341,696 B

  convert_kernel<<<4224, 256, 0, stream>>>(H, wq, wk, wv, wo, Hb, Wqkv, Wob);
  gemm0_kernel<<<1152, 256, 0, stream>>>(Hb, Wqkv, Qpb, Kpb, Vtb, p, s, compat, gamma);
  attn_kernel<<<768, 256, 0, stream>>>(Qpb, Kpb, Vtb, Ctx);
  gemm1_kernel<<<dim3(128, 6), 256, 0, stream>>>(Ctx, Wob, bo, out);
}

// Round 14
// 136.897 us; speedup vs baseline: 1.0887x; 1.0887x over previous
//
#include <hip/hip_runtime.h>
#include <stdint.h>

#define TT 2048
#define DD 768
#define NHEAD 12
#define DH 64
#define MM 8192   // B*T
#define DP 80     // padded head dim (64 data + 6 bias + 10 zero)

typedef __attribute__((ext_vector_type(8))) short bf16x8;
typedef __attribute__((ext_vector_type(4))) float f32x4;
typedef __attribute__((ext_vector_type(16))) float f32x16;
typedef __attribute__((ext_vector_type(2))) unsigned int u32x2v;
typedef unsigned short u16;

#define GAS __attribute__((address_space(1)))
#define LAS __attribute__((address_space(3)))

static __device__ __forceinline__ void gload16(const void* g, void* l) {
  __builtin_amdgcn_global_load_lds((const GAS uint32_t*)g, (LAS uint32_t*)l, 16, 0, 0);
}

static __device__ __forceinline__ u16 f2b(float f) {
  union { float f; uint32_t u; } x; x.f = f;
  uint32_t r = x.u + 0x7fffu + ((x.u >> 16) & 1u);
  return (u16)(r >> 16);
}
static __device__ __forceinline__ float b2f(u16 v) {
  union { uint32_t u; float f; } x; x.u = ((uint32_t)v) << 16; return x.f;
}

#if __has_builtin(__builtin_amdgcn_exp2f)
#define EXP2(x) __builtin_amdgcn_exp2f(x)
#else
#define EXP2(x) exp2f(x)
#endif

static __device__ __forceinline__ void pswap(uint32_t& a, uint32_t& b) {
#if __has_builtin(__builtin_amdgcn_permlane32_swap)
  u32x2v r = __builtin_amdgcn_permlane32_swap(a, b, false, false);
  a = r[0]; b = r[1];
#else
  uint32_t ax = (uint32_t)__shfl_xor((int)a, 32, 64);
  uint32_t bx = (uint32_t)__shfl_xor((int)b, 32, 64);
  bool lo = (threadIdx.x & 32) == 0;
  uint32_t na = lo ? a : bx, nb = lo ? ax : b;
  a = na; b = nb;
#endif
}
static __device__ __forceinline__ float pswap_add(float x) {
  uint32_t a = __float_as_uint(x), b = a; pswap(a, b);
  return __uint_as_float(a) + __uint_as_float(b);
}
static __device__ __forceinline__ uint32_t cvtpk(float lo, float hi_) {
  uint32_t r;
  asm("v_cvt_pk_bf16_f32 %0, %1, %2" : "=v"(r) : "v"(lo), "v"(hi_));
  return r;
}
static __device__ __forceinline__ f32x16 mfma32(bf16x8 a, bf16x8 b, f32x16 c) {
  return __builtin_amdgcn_mfma_f32_32x32x16_bf16(a, b, c, 0, 0, 0);
}

// ---------------- convert f32 -> bf16 (pure streaming, 8 el/thread) ----------------
__global__ __launch_bounds__(256) void convert_kernel(
    const float* __restrict__ H, const float* __restrict__ wq,
    const float* __restrict__ wk, const float* __restrict__ wv,
    const float* __restrict__ wo,
    u16* __restrict__ Hb, u16* __restrict__ Wqkv, u16* __restrict__ Wob) {
  const size_t NHEL = (size_t)MM * DD;     // 6291456 (mult of 8)
  const size_t NW = (size_t)DD * DD;       // 589824  (mult of 8)
  size_t i = ((size_t)blockIdx.x * 256 + threadIdx.x) * 8;
  const float* src; u16* dst; size_t so, dofs;
  if (i < NHEL) { src = H; so = i; dst = Hb; dofs = i; }
  else if (i < NHEL + 3 * NW) {
    size_t j = i - NHEL; dst = Wqkv; dofs = j;
    if (j < NW) { src = wq; so = j; }
    else if (j < 2 * NW) { src = wk; so = j - NW; }
    else { src = wv; so = j - 2 * NW; }
  } else if (i < NHEL + 4 * NW) {
    size_t j = i - NHEL - 3 * NW; src = wo; so = j; dst = Wob; dofs = j;
  } else return;
  float4 v0 = *(const float4*)&src[so];
  float4 v1 = *(const float4*)&src[so + 4];
  union { u16 u[8]; uint4 v; } o;
  o.u[0] = f2b(v0.x); o.u[1] = f2b(v0.y); o.u[2] = f2b(v0.z); o.u[3] = f2b(v0.w);
  o.u[4] = f2b(v1.x); o.u[5] = f2b(v1.y); o.u[6] = f2b(v1.z); o.u[7] = f2b(v1.w);
  *(uint4*)&dst[dofs] = o.v;
}

// ---------------- GEMM (MODE 0): QKV proj, 128x128 tile, 32x32x16 MFMA ----------------
// Inner loop on v_mfma_f32_32x32x16_bf16 (2495 TF ceiling vs 2075 for 16x16,
// half the issue slots). Fragment mappings identical to the attn kernel's
// verified usage: A/B lane->(row=lane&31, k=(lane>>5)*8 within 16-slice),
// C/D row=(z&3)+8*(z>>2)+4*hi, col=lane&31.
__global__ __launch_bounds__(256) void gemm0_kernel(
    const u16* __restrict__ A, const u16* __restrict__ Bw,
    u16* __restrict__ Qp, u16* __restrict__ Kp, u16* __restrict__ Vt,
    const float* __restrict__ Pp, const float* __restrict__ Sp,
    const float* __restrict__ compat, const float* __restrict__ gamma) {
  __shared__ u16 SMEM[17408];                 // As(8192) + Bs(8192); Ct overlays (128*136)
  u16* As = SMEM;
  u16* Bs = SMEM + 8192;
  const int tid = threadIdx.x;
  const int lane = tid & 63, w = tid >> 6;
  const int wr = w >> 1, wc = w & 1;
  const int ql = lane & 31, hi = lane >> 5;
  const int lin = blockIdx.x;
  const int swz = (lin & 7) * 144 + (lin >> 3);
  const int m0 = (swz / 18) * 128, n0 = (swz % 18) * 128;

  f32x16 acc[2][2];
#pragma unroll
  for (int mi = 0; mi < 2; ++mi)
#pragma unroll
    for (int ni = 0; ni < 2; ++ni)
#pragma unroll
      for (int z = 0; z < 16; ++z) acc[mi][ni][z] = 0.f;

  for (int ks = 0; ks < 12; ++ks) {
    const int k0 = ks * 64;
    __syncthreads();
#pragma unroll
    for (int ii = 0; ii < 4; ++ii) {
      int seg = (w * 4 + ii) * 64 + lane;
      int row = seg >> 3, cs = seg & 7;
      int csw = cs ^ (row & 7);
      // each gload16 covers 64 lanes x 16B = 1024B = 512 u16 -> dest stride *512
      gload16(&A[(size_t)(m0 + row) * DD + k0 + csw * 8], &As[(w * 4 + ii) * 512]);
      gload16(&Bw[(size_t)(n0 + row) * DD + k0 + csw * 8], &Bs[(w * 4 + ii) * 512]);
    }
    __syncthreads();
#pragma unroll
    for (int ksl = 0; ksl < 4; ++ksl) {       // k-slice of 16 within BK=64
      const int g8 = 2 * ksl + hi;            // 8-u16 granule index (0..7)
      bf16x8 af[2], bfr[2];
#pragma unroll
      for (int mi = 0; mi < 2; ++mi) {
        int row = wr * 64 + mi * 32 + ql;
        af[mi] = *(const bf16x8*)&As[row * 64 + (g8 ^ (row & 7)) * 8];
      }
#pragma unroll
      for (int ni = 0; ni < 2; ++ni) {
        int row = wc * 64 + ni * 32 + ql;
        bfr[ni] = *(const bf16x8*)&Bs[row * 64 + (g8 ^ (row & 7)) * 8];
      }
#pragma unroll
      for (int mi = 0; mi < 2; ++mi)
#pragma unroll
        for (int ni = 0; ni < 2; ++ni)
          acc[mi][ni] = mfma32(af[mi], bfr[ni], acc[mi][ni]);
    }
  }

  const int sel = n0 / DD;            // 0=Q 1=K 2=V  (tiles never straddle)
  const int e0b = n0 - sel * DD;      // head-block base, h0 = e0b>>6
  const int bb = m0 >> 11;            // batch
  const int tb = m0 & (TT - 1);       // token base (multiple of 128)
  __syncthreads();                    // all LDS reads of As/Bs done
#pragma unroll
  for (int mi = 0; mi < 2; ++mi) {
#pragma unroll
    for (int ni = 0; ni < 2; ++ni) {
#pragma unroll
      for (int z = 0; z < 16; ++z) {
        float v = acc[mi][ni][z];
        int t = wr * 64 + mi * 32 + (z & 3) + 8 * (z >> 2) + 4 * hi;  // local token
        int c = wc * 64 + ni * 32 + ql;                               // local N col
        u16 bv = f2b(sel == 0 ? v * 0.18033688f : v);  // Q: *0.125*log2(e)
        if (sel < 2) SMEM[t * 136 + c] = bv;      // Ct[t][c]
        else         SMEM[c * 136 + t] = bv;      // Ct[dh][t] (transposed)
      }
    }
  }
  __syncthreads();
  if (sel < 2) {
    u16* base = (sel == 0) ? Qp : Kp;
    const int grp = tid >> 3, li = tid & 7;       // 32 groups x 8 lanes
#pragma unroll
    for (int it = 0; it < 8; ++it) {
      int chunk = it * 32 + grp;                  // 0..255
      int t = chunk & 127, hh = chunk >> 7;
      int h = (e0b >> 6) + hh;
      size_t row = ((size_t)(bb * NHEAD + h) * TT + tb + t) * DP;
      uint4 d = *(const uint4*)&SMEM[t * 136 + hh * 64 + li * 8];
      *(uint4*)&base[row + li * 8] = d;
    }
    // ---- bias dims 64..79: one (t,hh) chunk per thread, 32B each ----
    {
      const float L2E = 1.44269504f;
      int t = tid & 127, hh = tid >> 7;
      int h = (e0b >> 6) + hh;
      size_t ip = (size_t)bb * TT + tb + t;
      float p0 = Pp[ip * 2], p1 = Pp[ip * 2 + 1];
      union { u16 u[8]; uint4 v; } bias;
      union { u16 u[8]; uint4 v; } zz;
#pragma unroll
      for (int z = 0; z < 8; ++z) zz.u[z] = 0;
      if (sel == 0) {
        float c00 = compat[h * 4 + 0], c01 = compat[h * 4 + 1];
        float c10 = compat[h * 4 + 2], c11 = compat[h * 4 + 3];
        u16 q0 = f2b((p0 * c00 + p1 * c10) * L2E);
        u16 q1 = f2b((p0 * c01 + p1 * c11) * L2E);
        u16 gmb = f2b(gamma[0] * L2E);
        bias.u[0] = q0; bias.u[1] = q0; bias.u[2] = q1; bias.u[3] = q1;
        bias.u[4] = gmb; bias.u[5] = gmb; bias.u[6] = 0; bias.u[7] = 0;
      } else {
        float sv = Sp[ip];
        u16 p0h = f2b(p0); u16 p0l = f2b(p0 - b2f(p0h));
        u16 p1h = f2b(p1); u16 p1l = f2b(p1 - b2f(p1h));
        u16 svh = f2b(sv); u16 svl = f2b(sv - b2f(svh));
        bias.u[0] = p0h; bias.u[1] = p0l; bias.u[2] = p1h; bias.u[3] = p1l;
        bias.u[4] = svh; bias.u[5] = svl; bias.u[6] = 0; bias.u[7] = 0;
      }
      size_t row = ((size_t)(bb * NHEAD + h) * TT + tb + t) * DP;
      *(uint4*)&base[row + 64] = bias.v;
      *(uint4*)&base[row + 72] = zz.v;
    }
  } else {
    const int grp = tid >> 4, li = tid & 15;      // 16 groups x 16 lanes
#pragma unroll
    for (int it = 0; it < 8; ++it) {
      int c = it * 16 + grp;                      // 0..127
      int h = (e0b >> 6) + (c >> 6), dh = c & 63;
      size_t row = ((size_t)(bb * NHEAD + h)) * DH * TT + (size_t)dh * TT + tb;
      uint4 d = *(const uint4*)&SMEM[c * 136 + li * 8];
      *(uint4*)&Vt[row + li * 8] = d;
    }
  }
}

// ---------------- GEMM (MODE 1): out-proj, 64x128 tile, 768 blocks (3/CU) ----
__global__ __launch_bounds__(256) void gemm1_kernel(
    const u16* __restrict__ A, const u16* __restrict__ Bw,
    const float* __restrict__ bo, float* __restrict__ Out) {
  __shared__ u16 SMEM[12288];                 // As 64x64 (4096) + Bs 128x64 (8192)
  u16* As = SMEM;
  u16* Bs = SMEM + 4096;
  const int tid = threadIdx.x;
  const int lane = tid & 63, w = tid >> 6;
  const int wr = w & 1, wc = w >> 1;          // wave: 32(M) x 64(N)
  const int g = lane >> 4, r = lane & 15;
  const int m0 = blockIdx.x * 64, n0 = blockIdx.y * 128;

  f32x4 acc[2][4];
#pragma unroll
  for (int m = 0; m < 2; ++m)
#pragma unroll
    for (int n = 0; n < 4; ++n) acc[m][n] = (f32x4){0.f, 0.f, 0.f, 0.f};

  for (int ks = 0; ks < 12; ++ks) {
    const int k0 = ks * 64;
    __syncthreads();
#pragma unroll
    for (int i = 0; i < 6; ++i) {             // 24 chunks over 4 waves
      int idx = w + 4 * i;
      if (idx < 8) {                          // A chunks 0..7 (64 rows)
        int n = idx * 64 + lane;
        int row = n >> 3, cs = n & 7;
        int csw = cs ^ (row & 7);
        gload16(&A[(size_t)(m0 + row) * DD + k0 + csw * 8], &As[idx * 512]);
      } else {                                // B chunks 0..15 (128 rows)
        int j = idx - 8;
        int n = j * 64 + lane;
        int row = n >> 3, cs = n & 7;
        int csw = cs ^ (row & 7);
        gload16(&Bw[(size_t)(n0 + row) * DD + k0 + csw * 8], &Bs[j * 512]);
      }
    }
    __syncthreads();
#pragma unroll
    for (int kk = 0; kk < 2; ++kk) {
      bf16x8 af[2], bfr[4];
#pragma unroll
      for (int m = 0; m < 2; ++m) {
        int row = wr * 32 + m * 16 + r;
        int ch = (kk * 4 + g) ^ (row & 7);
        af[m] = *(const bf16x8*)&As[row * 64 + ch * 8];
      }
#pragma unroll
      for (int n = 0; n < 4; ++n) {
        int row = wc * 64 + n * 16 + r;
        int ch = (kk * 4 + g) ^ (row & 7);
        bfr[n] = *(const bf16x8*)&Bs[row * 64 + ch * 8];
      }
#pragma unroll
      for (int m = 0; m < 2; ++m)
#pragma unroll
        for (int n = 0; n < 4; ++n)
          acc[m][n] = __builtin_amdgcn_mfma_f32_16x16x32_bf16(af[m], bfr[n], acc[m][n], 0, 0, 0);
    }
  }

#pragma unroll
  for (int m = 0; m < 2; ++m) {
#pragma unroll
    for (int n = 0; n < 4; ++n) {
#pragma unroll
      for (int reg = 0; reg < 4; ++reg) {
        int gt = m0 + wr * 32 + m * 16 + g * 4 + reg;
        int e = n0 + wc * 64 + n * 16 + r;
        Out[(size_t)gt * DD + e] = acc[m][n][reg] + bo[e];
      }
    }
  }
}

// ---------------- attention: swapped QK^T, fixed-base softmax (m=0) ----------------
// R12-measured-best form: 4 waves x 32 q, full 64-key tile per wave, single
// barrier per tile, K/V double-buffered via global_load_lds; l on VALU
// (partial sum before PV), one pswap_add + 16-bpermute epilogue.
#define QB 128
__global__ __launch_bounds__(256, 3) void attn_kernel(
    const u16* __restrict__ Qp, const u16* __restrict__ Kp, const u16* __restrict__ Vtb,
    u16* __restrict__ Ctx) {
  __shared__ u16 Ks[2][64 * 88];   // 64 rows x 176B (160B data + 16B pad-dup)
  __shared__ u16 Vs[2][64 * 64];   // [dh][key], source pre-swizzled
  const int tid = threadIdx.x, lane = tid & 63, w = tid >> 6;
  const int hi = lane >> 5, ql = lane & 31;
  const int bid = blockIdx.x;
  const int bh = bid % 48, qb = bid / 48;   // bh-major: same bh -> same XCD
  const int b = bh / NHEAD, h = bh % NHEAD;

  const char* KgB = (const char*)(Kp + (size_t)bh * TT * DP);
  const char* VgB = (const char*)(Vtb + (size_t)bh * DH * TT);
  const u16* Qg = Qp + (size_t)bh * TT * DP;

  const int q = qb * QB + w * 32 + ql;
  bf16x8 Qf[5];
#pragma unroll
  for (int kbl = 0; kbl < 5; ++kbl)
    Qf[kbl] = *(const bf16x8*)&Qg[(size_t)q * DP + (2 * kbl + hi) * 8];

  auto kofs = [&](int i) {
    int n = i * 64 + lane;
    int rr = (n * 2979) >> 15;       // n/11 exact for n<768
    int c = n - 11 * rr; if (c > 9) c = 9;
    return rr * 160 + c * 16;
  };
  auto vofs = [&](int j) {
    int n = j * 64 + lane;
    int dh = n >> 3, cs = n & 7;
    return dh * 4096 + (cs ^ (dh & 7)) * 16;
  };
  const int koff0 = kofs(w), koff1 = kofs(w + 4), koff2 = (w < 3) ? kofs(w + 8) : 0;
  const int voff0 = vofs(w), voff1 = vofs(w + 4);

  auto STAGE = [&](int nb, int t0) {
    const char* ksrc = KgB + (size_t)t0 * 160;
    char* kd = (char*)&Ks[nb][0];
    gload16(ksrc + koff0, kd + w * 1024);
    gload16(ksrc + koff1, kd + (w + 4) * 1024);
    if (w < 3) gload16(ksrc + koff2, kd + (w + 8) * 1024);
    const char* vsrc = VgB + (size_t)t0 * 2;
    char* vd = (char*)&Vs[nb][0];
    gload16(vsrc + voff0, vd + w * 1024);
    gload16(vsrc + voff1, vd + (w + 4) * 1024);
  };

  f32x16 o0, o1;
#pragma unroll
  for (int z = 0; z < 16; ++z) { o0[z] = 0.f; o1[z] = 0.f; }
  float l_st = 0.f;

  STAGE(0, 0);

  for (int kt = 0; kt < 32; ++kt) {
    __syncthreads();                       // drains vmcnt: current buffers valid
    if (kt + 1 < 32) STAGE((kt + 1) & 1, (kt + 1) * 64);
    const u16* Kb_ = &Ks[kt & 1][0];
    const u16* Vb_ = &Vs[kt & 1][0];

    // S^T = K' * Q'^T : rows=keys, cols=q (lane&31). Two 32-key blocks.
    f32x16 s0, s1;
#pragma unroll
    for (int z = 0; z < 16; ++z) { s0[z] = 0.f; s1[z] = 0.f; }
    __builtin_amdgcn_s_setprio(1);
#pragma unroll
    for (int kbl = 0; kbl < 5; ++kbl) {
      bf16x8 a0 = *(const bf16x8*)&Kb_[ql * 88 + hi * 8 + kbl * 16];
      s0 = mfma32(a0, Qf[kbl], s0);
    }
#pragma unroll
    for (int kbl = 0; kbl < 5; ++kbl) {
      bf16x8 a1 = *(const bf16x8*)&Kb_[(ql + 32) * 88 + hi * 8 + kbl * 16];
      s1 = mfma32(a1, Qf[kbl], s1);
    }
    __builtin_amdgcn_s_setprio(0);

    // P = exp2(S) directly (fixed base m=0); VALU l partial sum
    float p_[32];
#pragma unroll
    for (int z = 0; z < 16; ++z) p_[z] = EXP2(s0[z]);
#pragma unroll
    for (int z = 0; z < 16; ++z) p_[16 + z] = EXP2(s1[z]);
    float ts = 0.f;
#pragma unroll
    for (int z = 0; z < 32; ++z) ts += p_[z];
    l_st += ts;

    // build PA fragments in-register (cvt_pk + permlane32_swap); PV
    __builtin_amdgcn_s_setprio(1);
#pragma unroll
    for (int ks = 0; ks < 4; ++ks) {
      const int base = ks * 8;
      uint32_t wa = cvtpk(p_[base + 0], p_[base + 1]);
      uint32_t wb = cvtpk(p_[base + 4], p_[base + 5]);
      uint32_t wc = cvtpk(p_[base + 2], p_[base + 3]);
      uint32_t wd = cvtpk(p_[base + 6], p_[base + 7]);
      pswap(wa, wb);
      pswap(wc, wd);
      union { uint32_t u[4]; bf16x8 v; } pa;
      pa.u[0] = wa; pa.u[1] = wc; pa.u[2] = wb; pa.u[3] = wd;
#pragma unroll
      for (int nb = 0; nb < 2; ++nb) {
        int row = ql + 32 * nb;
        bf16x8 vf = *(const bf16x8*)&Vb_[row * 64 + (((2 * ks + hi) ^ (ql & 7)) * 8)];
        if (nb == 0) o0 = mfma32(pa.v, vf, o0);
        else         o1 = mfma32(pa.v, vf, o1);
      }
    }
    __builtin_amdgcn_s_setprio(0);
  }

  // epilogue: combine hi-halves of l once, broadcast 1/l from lane q2
  float lfull = pswap_add(l_st);            // lanes ql and ql+32 both hold l(q=ql)
  float invl = 1.0f / lfull;
#pragma unroll
  for (int z = 0; z < 16; ++z) {
    int q2 = (z & 3) + 8 * (z >> 2) + 4 * hi;
    float il = __uint_as_float(__builtin_amdgcn_ds_bpermute(q2 * 4, __float_as_uint(invl)));
    int qrow = qb * QB + w * 32 + q2;
    size_t rowb = ((size_t)b * TT + qrow) * DD + h * DH;
    Ctx[rowb + ql]      = f2b(o0[z] * il);
    Ctx[rowb + ql + 32] = f2b(o1[z] * il);
  }
}

extern "C" void kernel_launch(void* const* d_in, const int* in_sizes, int n_in,
                              void* d_out, int out_size, void* d_ws, size_t ws_size,
                              hipStream_t stream) {
  const float* H = (const float*)d_in[0];
  const float* p = (const float*)d_in[1];
  const float* s = (const float*)d_in[2];
  const float* wq = (const float*)d_in[3];
  const float* wk = (const float*)d_in[4];
  const float* wv = (const float*)d_in[5];
  const float* wo = (const float*)d_in[6];
  const float* bo = (const float*)d_in[7];
  const float* compat = (const float*)d_in[8];
  const float* gamma = (const float*)d_in[9];
  float* out = (float*)d_out;

  char* ws = (char*)d_ws;
  u16* Hb   = (u16*)(ws);               // 12,582,912 B (dead after gemm0 -> Ctx)
  u16* Wqkv = (u16*)(ws + 12582912);    //  3,538,944 B
  u16* Wob  = (u16*)(ws + 16121856);    //  1,179,648 B
  u16* Qpb  = (u16*)(ws + 17301504);    // 15,728,640 B  (B*H*T*80 bf16)
  u16* Kpb  = (u16*)(ws + 33030144);    // 15,728,640 B
  u16* Vtb  = (u16*)(ws + 48758784);    // 12,582,912 B  (written transposed by gemm0)
  u16* Ctx  = Hb;                       // alias: Hb dead after gemm0
  // total 61,341,696 B

  convert_kernel<<<4224, 256, 0, stream>>>(H, wq, wk, wv, wo, Hb, Wqkv, Wob);
  gemm0_kernel<<<1152, 256, 0, stream>>>(Hb, Wqkv, Qpb, Kpb, Vtb, p, s, compat, gamma);
  attn_kernel<<<768, 256, 0, stream>>>(Qpb, Kpb, Vtb, Ctx);
  gemm1_kernel<<<dim3(128, 6), 256, 0, stream>>>(Ctx, Wob, bo, out);
}